// Round 18
// baseline (5498.637 us; speedup 1.0000x reference)
//
#include <hip/hip_runtime.h>
#include <hip/hip_bf16.h>
#include <math.h>

#define B_SZ 8
#define NT 2048
#define M_TOT (B_SZ * NT)      // 16384
#define DM 1024
#define ZD 32
#define IN0 2080
#define HID 2048
#define OUT1 1024
#define NCH 13                 // silu + T1..T12 (T0 folded into bias)
#define PZ 1056                // pos(1024)+z(32) per chunk
#define KPZ (NCH * PZ)         // 13728
#define KCTX (NCH * DM)        // 13312
#define KPOS (NCH * DM)        // 13312
#define KZ (NCH * ZD)          // 416
#define K1 (NCH * HID)         // 26624
#define NPOS 4096
#define RMS_EPS 1e-6f

typedef __bf16 bf16;
typedef __bf16 bf16x4 __attribute__((ext_vector_type(4)));
typedef __bf16 bf16x8 __attribute__((ext_vector_type(8)));
typedef float f32x4 __attribute__((ext_vector_type(4)));

__device__ __forceinline__ void gload16(const void* g, void* l) {
    __builtin_amdgcn_global_load_lds(
        (const __attribute__((address_space(1))) void*)g,
        (__attribute__((address_space(3))) void*)l, 16, 0, 0);
}

__device__ __forceinline__ float rb(float x) { return (float)(bf16)x; }

__device__ __forceinline__ unsigned pk2(float lo, float hi) {
    return (__builtin_bit_cast(unsigned, hi) & 0xFFFF0000u) |
           (__builtin_bit_cast(unsigned, lo) >> 16);
}
__device__ __forceinline__ float up_lo(unsigned u) { return __builtin_bit_cast(float, u << 16); }
__device__ __forceinline__ float up_hi(unsigned u) { return __builtin_bit_cast(float, u & 0xFFFF0000u); }

// ------------------------------------- layer-0 weight convert, split ctx / pos+z
__global__ __launch_bounds__(256) void convert_w0(const float* __restrict__ base,
                                                  const float* __restrict__ poly,
                                                  bf16* __restrict__ wctx,
                                                  bf16* __restrict__ wposz) {
    __shared__ float tile[32][33];
    int c = blockIdx.z;
    const float* src = (c == 0) ? base : (poly + (size_t)c * IN0 * HID);
    int i0 = blockIdx.x * 32, n0 = blockIdx.y * 32;
    int tx = threadIdx.x, ty = threadIdx.y;
#pragma unroll
    for (int r = 0; r < 4; r++)
        tile[ty + r * 8][tx] = src[(size_t)(i0 + ty + r * 8) * HID + n0 + tx];
    __syncthreads();
#pragma unroll
    for (int r = 0; r < 4; r++) {
        int n = n0 + ty + r * 8;
        int i = i0 + tx;
        bf16 v = (bf16)tile[tx][ty + r * 8];
        if (i < 1024) wctx[(size_t)n * KCTX + (size_t)c * 1024 + i] = v;
        else          wposz[(size_t)n * KPZ + (size_t)c * PZ + (i - 1024)] = v;
    }
}

__global__ __launch_bounds__(256) void convert_w(const float* __restrict__ base,
                                                 const float* __restrict__ poly,
                                                 bf16* __restrict__ dst, int IN, int OUT) {
    __shared__ float tile[32][33];
    int c = blockIdx.z;
    const float* src = (c == 0) ? base : (poly + (size_t)c * IN * OUT);
    int i0 = blockIdx.x * 32, n0 = blockIdx.y * 32;
    int tx = threadIdx.x, ty = threadIdx.y;
#pragma unroll
    for (int r = 0; r < 4; r++)
        tile[ty + r * 8][tx] = src[(size_t)(i0 + ty + r * 8) * OUT + n0 + tx];
    __syncthreads();
    size_t ldd = (size_t)NCH * IN;
#pragma unroll
    for (int r = 0; r < 4; r++) {
        int n = n0 + ty + r * 8;
        int i = i0 + tx;
        dst[(size_t)n * ldd + (size_t)c * IN + i] = (bf16)tile[tx][ty + r * 8];
    }
}

// ---------------- bias[n] = f32-sum_i bf16(poly[0][i][n])
__global__ void col_sum_s1(const float* __restrict__ w, float* __restrict__ partial,
                           int IN, int OUT) {
    __shared__ float sm[4][64];
    int tx = threadIdx.x, ty = threadIdx.y;
    int n = blockIdx.x * 64 + tx;
    int s = blockIdx.y;
    float acc = 0.f;
    for (int i = 4 * s + ty; i < IN; i += 128) acc += (float)(bf16)w[(size_t)i * OUT + n];
    sm[ty][tx] = acc;
    __syncthreads();
    if (ty == 0) partial[(size_t)s * OUT + n] = sm[0][tx] + sm[1][tx] + sm[2][tx] + sm[3][tx];
}
__global__ void col_sum_s2(const float* __restrict__ partial, float* __restrict__ bias, int OUT) {
    int n = blockIdx.x * 256 + threadIdx.x;
    if (n >= OUT) return;
    float s = 0.f;
#pragma unroll
    for (int k = 0; k < 32; k++) s += partial[(size_t)k * OUT + n];
    bias[n] = s;
}

// ------------------------------------------------------------ feature build
// silu with PER-OP bf16 rounding; tanh/Chebyshev in f32 (frozen numerics path).
__device__ __forceinline__ void write_features4(bf16* __restrict__ row, int i,
                                                float4 o, int stride) {
    float x[4] = {o.x, o.y, o.z, o.w};
    bf16x4 t;
#pragma unroll
    for (int l = 0; l < 4; l++) {
        float xb = rb(x[l]);
        float e  = rb(expf(-xb));
        float d  = rb(1.f + e);
        float sg = rb(1.f / d);
        t[l] = (bf16)(xb * sg);
    }
    *(bf16x4*)&row[i] = t;
    float xs[4], Tp[4], Tc[4];
#pragma unroll
    for (int l = 0; l < 4; l++) {
        xs[l] = tanhf(x[l]);
        Tp[l] = 1.f; Tc[l] = xs[l];
        t[l] = (bf16)xs[l];
    }
    *(bf16x4*)&row[(size_t)stride + i] = t;
#pragma unroll
    for (int k = 2; k < NCH; k++) {
#pragma unroll
        for (int l = 0; l < 4; l++) {
            float Tn = 2.f * xs[l] * Tc[l] - Tp[l];
            t[l] = (bf16)Tn;
            Tp[l] = Tc[l]; Tc[l] = Tn;
        }
        *(bf16x4*)&row[(size_t)k * stride + i] = t;
    }
}

// 8-wide variant: identical per-element math, 16B stores
__device__ __forceinline__ void write_features8(bf16* __restrict__ row, int i,
                                                const float* __restrict__ x, int stride) {
    bf16x8 t;
#pragma unroll
    for (int l = 0; l < 8; l++) {
        float xb = rb(x[l]);
        float e  = rb(expf(-xb));
        float d  = rb(1.f + e);
        float sg = rb(1.f / d);
        t[l] = (bf16)(xb * sg);
    }
    *(bf16x8*)&row[i] = t;
    float xs[8], Tp[8], Tc[8];
#pragma unroll
    for (int l = 0; l < 8; l++) {
        xs[l] = tanhf(x[l]);
        Tp[l] = 1.f; Tc[l] = xs[l];
        t[l] = (bf16)xs[l];
    }
    *(bf16x8*)&row[(size_t)stride + i] = t;
#pragma unroll
    for (int k = 2; k < NCH; k++) {
#pragma unroll
        for (int l = 0; l < 8; l++) {
            float Tn = 2.f * xs[l] * Tc[l] - Tp[l];
            t[l] = (bf16)Tn;
            Tp[l] = Tc[l]; Tc[l] = Tn;
        }
        *(bf16x8*)&row[(size_t)k * stride + i] = t;
    }
}

__global__ __launch_bounds__(256) void build_fctx(const float* __restrict__ h_x,
                                                  bf16* __restrict__ Fctx) {
    int id = blockIdx.x * 256 + threadIdx.x;
    int b = id >> 8;
    int i = (id & 255) * 4;
    float4 v = *(const float4*)&h_x[((size_t)b * 128 + 127) * DM + i];
    write_features4(Fctx + (size_t)b * KCTX, i, v, DM);
}

__global__ void ctx_dot(const bf16* __restrict__ Fctx, const bf16* __restrict__ wctx,
                        float* __restrict__ ctx_part) {
    __shared__ float sm[4][64];
    int tx = threadIdx.x, ty = threadIdx.y;
    int n = blockIdx.x * 64 + tx;
    int c = blockIdx.y, b = blockIdx.z;
    const bf16* f = Fctx + ((size_t)b * NCH + c) * DM;
    const bf16* wv = wctx + (size_t)n * KCTX + (size_t)c * DM;
    float s = 0.f;
    for (int i = ty; i < DM; i += 4) s += (float)f[i] * (float)wv[i];
    sm[ty][tx] = s;
    __syncthreads();
    if (ty == 0) ctx_part[((size_t)b * NCH + c) * HID + n] = sm[0][tx] + sm[1][tx] + sm[2][tx] + sm[3][tx];
}

// pos table: 2048 blocks x 256 thr, 8 elements/thread
__global__ __launch_bounds__(256) void build_fpos(const float* __restrict__ pe,
                                                  bf16* __restrict__ Fpos) {
    int id = blockIdx.x * 256 + threadIdx.x;   // 4096 * 128
    int p = id >> 7;
    int i = (id & 127) * 8;
    float x[8];
    *(float4*)&x[0] = *(const float4*)&pe[(size_t)p * DM + i];
    *(float4*)&x[4] = *(const float4*)&pe[(size_t)p * DM + i + 4];
    write_features8(Fpos + (size_t)p * KPOS, i, x, DM);
}

// z features: 8 elements/thread (4 threads/row)
__global__ __launch_bounds__(256) void build_fz(const float* __restrict__ z,
                                                bf16* __restrict__ Fz) {
    int id = blockIdx.x * 256 + threadIdx.x;   // M_TOT * 4
    if (id >= M_TOT * (ZD / 8)) return;
    int ml = id >> 2;
    int i = (id & 3) * 8;
    float x[8];
    *(float4*)&x[0] = *(const float4*)&z[(size_t)ml * ZD + i];
    *(float4*)&x[4] = *(const float4*)&z[(size_t)ml * ZD + i + 4];
    write_features8(Fz + (size_t)ml * KZ, i, x, ZD);
}

// ---------------------------------------------- fused RMSNorm + layer-1 feature build
__global__ __launch_bounds__(256) void rmsnorm_feat(const bf16* __restrict__ H,
                                                    const float* __restrict__ scale,
                                                    bf16* __restrict__ F) {
    int row = blockIdx.x;
    int t = threadIdx.x;
    bf16x8 h = *(const bf16x8*)&H[(size_t)row * HID + t * 8];
    float f[8];
    float s = 0.f;
#pragma unroll
    for (int l = 0; l < 8; l++) { f[l] = (float)h[l]; s += f[l] * f[l]; }
#pragma unroll
    for (int o = 32; o > 0; o >>= 1) s += __shfl_down(s, o, 64);
    __shared__ float wsum[4];
    if ((t & 63) == 0) wsum[t >> 6] = s;
    __syncthreads();
    s = wsum[0] + wsum[1] + wsum[2] + wsum[3];
    float rs = rsqrtf(s * (1.0f / HID) + RMS_EPS);
    const float4* sc = (const float4*)scale;
    float4 sv0 = sc[t * 2], sv1 = sc[t * 2 + 1];
    bf16* Frow = F + (size_t)row * K1;
    float x[8];
    x[0] = f[0] * rs * sv0.x; x[1] = f[1] * rs * sv0.y;
    x[2] = f[2] * rs * sv0.z; x[3] = f[3] * rs * sv0.w;
    x[4] = f[4] * rs * sv1.x; x[5] = f[5] * rs * sv1.y;
    x[6] = f[6] * rs * sv1.z; x[7] = f[7] * rs * sv1.w;
    write_features8(Frow, t * 8, x, HID);
}

// ------------------------------------------------------------------ final RMSNorm (in place)
template <int N>
__global__ __launch_bounds__(256) void rmsnorm_k(float* __restrict__ H,
                                                 const float* __restrict__ scale) {
    constexpr int VPT = N / (4 * 256);
    int row = blockIdx.x;
    float4* p = (float4*)(H + (size_t)row * N);
    const float4* sc = (const float4*)scale;
    float4 v[VPT];
    float s = 0.f;
#pragma unroll
    for (int j = 0; j < VPT; j++) {
        v[j] = p[threadIdx.x + j * 256];
        s += v[j].x * v[j].x + v[j].y * v[j].y + v[j].z * v[j].z + v[j].w * v[j].w;
    }
#pragma unroll
    for (int o = 32; o > 0; o >>= 1) s += __shfl_down(s, o, 64);
    __shared__ float wsum[4];
    if ((threadIdx.x & 63) == 0) wsum[threadIdx.x >> 6] = s;
    __syncthreads();
    s = wsum[0] + wsum[1] + wsum[2] + wsum[3];
    float rs = rsqrtf(s * (1.0f / N) + RMS_EPS);
#pragma unroll
    for (int j = 0; j < VPT; j++) {
        float4 sv = sc[threadIdx.x + j * 256];
        float4 o_;
        o_.x = v[j].x * rs * sv.x;
        o_.y = v[j].y * rs * sv.y;
        o_.z = v[j].z * rs * sv.z;
        o_.w = v[j].w * rs * sv.w;
        p[threadIdx.x + j * 256] = o_;
    }
}

// ============================ GEMM0: gather-A, BM128 x BN128, 256 thr, BK=64 (+32 z-step)
// R14-proven structure; __launch_bounds__(256,5) for occupancy (VGPR 64, LDS 32KB -> 5 blocks/CU)
#define BM0 128
#define BN0 128
#define GROUP_M 32

__global__ __launch_bounds__(256, 5) void gemm0_k(const bf16* __restrict__ Fpos,
                                                  const bf16* __restrict__ Fz,
                                                  const int* __restrict__ tp,
                                                  const bf16* __restrict__ Bt,
                                                  const float* __restrict__ bias,
                                                  const float* __restrict__ ctxp,
                                                  unsigned short* __restrict__ C) {
    __shared__ __align__(16) bf16 As[BM0 * 64];   // 16 KB
    __shared__ __align__(16) bf16 Bs[BN0 * 64];   // 16 KB

    const int N = HID;
    const int nbm = M_TOT / BM0, nbn = N / BN0;   // 128 x 16
    int pid = blockIdx.x;
    int width = GROUP_M * nbn;
    int group_id = pid / width;
    int first_m = group_id * GROUP_M;
    int gsz = min(nbm - first_m, GROUP_M);
    int mb = first_m + (pid % width) % gsz;
    int nb = (pid % width) / gsz;

    int t = threadIdx.x;
    int lane = t & 63, wid = t >> 6;
    int wm = wid >> 1, wn = wid & 1;              // 2x2 waves, 64x64 each

    const unsigned colx = (unsigned)(((t & 7) ^ ((t >> 3) & 7)) * 8);
    const unsigned colz = (unsigned)(((t & 3) ^ ((t >> 2) & 3)) * 8);
    unsigned offA[4];
#pragma unroll
    for (int i = 0; i < 4; i++)
        offA[i] = (unsigned)tp[mb * BM0 + (t >> 3) + i * 32] * KPOS + colx;
    unsigned offZA[2];
#pragma unroll
    for (int i = 0; i < 2; i++)
        offZA[i] = (unsigned)(mb * BM0 + (t >> 2) + i * 64) * KZ + colz;
    const unsigned offB  = (unsigned)(nb * BN0 + (t >> 3)) * KPZ + colx;
    const unsigned offBz = (unsigned)(nb * BN0 + (t >> 2)) * KPZ + colz + 1024u;

    const int arow = wm * 64 + (lane & 15);
    const int brow = wn * 64 + (lane & 15);
    const int kqo = (lane >> 4) * 8;

    const int lcol = lane & 15, lrow4 = (lane >> 4) * 4;
    const int crow0 = mb * BM0 + wm * 64;
    const int ccol0 = nb * BN0 + wn * 64;
    const int b = (mb * BM0) >> 11;

    unsigned outp[4][4][2] = {};

    for (int c = 0; c < NCH; c++) {
        f32x4 acc[4][4];
        {
            const float* cp = ctxp + ((size_t)b * NCH + c) * N;
#pragma unroll
            for (int bn = 0; bn < 4; bn++) {
                float cv = cp[ccol0 + bn * 16 + lcol];
#pragma unroll
                for (int am = 0; am < 4; am++) acc[am][bn] = (f32x4){cv, cv, cv, cv};
            }
        }
        // pos part: 16 steps of BK=64
        for (int ks = 0; ks < 1024; ks += 64) {
            unsigned co = (unsigned)c * 1024u + ks;
#pragma unroll
            for (int i = 0; i < 4; i++)
                gload16(Fpos + offA[i] + co, (char*)As + (t + i * 256) * 16);
            unsigned cb = (unsigned)c * PZ + ks;
#pragma unroll
            for (int i = 0; i < 4; i++)
                gload16(Bt + offB + (unsigned)i * (32u * KPZ) + cb, (char*)Bs + (t + i * 256) * 16);
            __syncthreads();
#pragma unroll
            for (int h = 0; h < 2; h++) {
                bf16x8 af[4], bfr[4];
#pragma unroll
                for (int am = 0; am < 4; am++) {
                    int L = (arow + am * 16) * 128 + h * 64 + kqo * 2;
                    int P = L ^ (((L >> 7) & 7) << 4);
                    af[am] = *(const bf16x8*)((const char*)As + P);
                }
#pragma unroll
                for (int bn = 0; bn < 4; bn++) {
                    int L = (brow + bn * 16) * 128 + h * 64 + kqo * 2;
                    int P = L ^ (((L >> 7) & 7) << 4);
                    bfr[bn] = *(const bf16x8*)((const char*)Bs + P);
                }
#pragma unroll
                for (int am = 0; am < 4; am++)
#pragma unroll
                    for (int bn = 0; bn < 4; bn++)
                        acc[am][bn] = __builtin_amdgcn_mfma_f32_16x16x32_bf16(af[am], bfr[bn], acc[am][bn], 0, 0, 0);
            }
            __syncthreads();
        }
        // z-step (BK=32), 64B rows
        {
#pragma unroll
            for (int i = 0; i < 2; i++)
                gload16(Fz + offZA[i] + (unsigned)c * 32u, (char*)As + (t + i * 256) * 16);
            unsigned cb = (unsigned)c * PZ;
#pragma unroll
            for (int i = 0; i < 2; i++)
                gload16(Bt + offBz + (unsigned)i * (64u * KPZ) + cb, (char*)Bs + (t + i * 256) * 16);
            __syncthreads();
            bf16x8 af[4], bfr[4];
#pragma unroll
            for (int am = 0; am < 4; am++) {
                int L = (arow + am * 16) * 64 + kqo * 2;
                int P = L ^ (((L >> 6) & 3) << 4);
                af[am] = *(const bf16x8*)((const char*)As + P);
            }
#pragma unroll
            for (int bn = 0; bn < 4; bn++) {
                int L = (brow + bn * 16) * 64 + kqo * 2;
                int P = L ^ (((L >> 6) & 3) << 4);
                bfr[bn] = *(const bf16x8*)((const char*)Bs + P);
            }
#pragma unroll
            for (int am = 0; am < 4; am++)
#pragma unroll
                for (int bn = 0; bn < 4; bn++)
                    acc[am][bn] = __builtin_amdgcn_mfma_f32_16x16x32_bf16(af[am], bfr[bn], acc[am][bn], 0, 0, 0);
            __syncthreads();
        }
        // fold
#pragma unroll
        for (int am = 0; am < 4; am++)
#pragma unroll
            for (int bn = 0; bn < 4; bn++)
#pragma unroll
                for (int ep = 0; ep < 2; ep++) {
                    float f0 = up_lo(outp[am][bn][ep]);
                    float f1 = up_hi(outp[am][bn][ep]);
                    f0 = rb(f0 + rb(acc[am][bn][ep * 2 + 0]));
                    f1 = rb(f1 + rb(acc[am][bn][ep * 2 + 1]));
                    outp[am][bn][ep] = pk2(f0, f1);
                }
        if (c == 0) {
#pragma unroll
            for (int bn = 0; bn < 4; bn++) {
                float bv = rb(bias[ccol0 + bn * 16 + lcol]);
#pragma unroll
                for (int am = 0; am < 4; am++)
#pragma unroll
                    for (int ep = 0; ep < 2; ep++) {
                        float f0 = rb(up_lo(outp[am][bn][ep]) + bv);
                        float f1 = rb(up_hi(outp[am][bn][ep]) + bv);
                        outp[am][bn][ep] = pk2(f0, f1);
                    }
            }
        }
    }

#pragma unroll
    for (int bn = 0; bn < 4; bn++) {
        int col = ccol0 + bn * 16 + lcol;
#pragma unroll
        for (int am = 0; am < 4; am++) {
            int row = crow0 + am * 16 + lrow4;
            C[(size_t)(row + 0) * N + col] = (unsigned short)(outp[am][bn][0] & 0xFFFFu);
            C[(size_t)(row + 1) * N + col] = (unsigned short)(outp[am][bn][0] >> 16);
            C[(size_t)(row + 2) * N + col] = (unsigned short)(outp[am][bn][1] & 0xFFFFu);
            C[(size_t)(row + 3) * N + col] = (unsigned short)(outp[am][bn][1] >> 16);
        }
    }
}

// ============================ GEMM1: dense-A, BM128 x BN128, 256 thr, BK=64
#define BM1 128
#define BN1 128

__global__ __launch_bounds__(256, 5) void gemm1_k(const bf16* __restrict__ A,
                                                  const bf16* __restrict__ Bt,
                                                  const float* __restrict__ bias,
                                                  float* __restrict__ C,
                                                  int Mrows) {
    __shared__ __align__(16) bf16 As[BM1 * 64];   // 16 KB
    __shared__ __align__(16) bf16 Bs[BN1 * 64];   // 16 KB

    const int N = OUT1, IN = HID, K = K1;
    const int nbm = Mrows / BM1, nbn = N / BN1;
    int pid = blockIdx.x;
    int width = GROUP_M * nbn;
    int group_id = pid / width;
    int first_m = group_id * GROUP_M;
    int gsz = min(nbm - first_m, GROUP_M);
    int mb = first_m + (pid % width) % gsz;
    int nb = (pid % width) / gsz;

    int t = threadIdx.x;
    int lane = t & 63, wid = t >> 6;
    int wm = wid >> 1, wn = wid & 1;              // 2x2 waves, 64x64 each

    const unsigned colx = (unsigned)(((t & 7) ^ ((t >> 3) & 7)) * 8);
    const unsigned offA = (unsigned)(mb * BM1 + (t >> 3)) * (unsigned)K + colx;
    const unsigned offB = (unsigned)(nb * BN1 + (t >> 3)) * (unsigned)K + colx;

    const int arow = wm * 64 + (lane & 15);
    const int brow = wn * 64 + (lane & 15);
    const int kqo = (lane >> 4) * 8;

    const int lcol = lane & 15, lrow4 = (lane >> 4) * 4;
    const int crow0 = mb * BM1 + wm * 64;
    const int ccol0 = nb * BN1 + wn * 64;

    unsigned outp[4][4][2] = {};

    for (int c = 0; c < NCH; c++) {
        f32x4 acc[4][4] = {};
        for (int ks = 0; ks < IN; ks += 64) {
            unsigned co = (unsigned)c * (unsigned)IN + ks;
#pragma unroll
            for (int i = 0; i < 4; i++) {
                gload16(A + offA + (unsigned)i * (32u * (unsigned)K) + co, (char*)As + (t + i * 256) * 16);
                gload16(Bt + offB + (unsigned)i * (32u * (unsigned)K) + co, (char*)Bs + (t + i * 256) * 16);
            }
            __syncthreads();
#pragma unroll
            for (int h = 0; h < 2; h++) {
                bf16x8 af[4], bfr[4];
#pragma unroll
                for (int am = 0; am < 4; am++) {
                    int L = (arow + am * 16) * 128 + h * 64 + kqo * 2;
                    int P = L ^ (((L >> 7) & 7) << 4);
                    af[am] = *(const bf16x8*)((const char*)As + P);
                }
#pragma unroll
                for (int bn = 0; bn < 4; bn++) {
                    int L = (brow + bn * 16) * 128 + h * 64 + kqo * 2;
                    int P = L ^ (((L >> 7) & 7) << 4);
                    bfr[bn] = *(const bf16x8*)((const char*)Bs + P);
                }
#pragma unroll
                for (int am = 0; am < 4; am++)
#pragma unroll
                    for (int bn = 0; bn < 4; bn++)
                        acc[am][bn] = __builtin_amdgcn_mfma_f32_16x16x32_bf16(af[am], bfr[bn], acc[am][bn], 0, 0, 0);
            }
            __syncthreads();
        }
#pragma unroll
        for (int am = 0; am < 4; am++)
#pragma unroll
            for (int bn = 0; bn < 4; bn++)
#pragma unroll
                for (int ep = 0; ep < 2; ep++) {
                    float f0 = up_lo(outp[am][bn][ep]);
                    float f1 = up_hi(outp[am][bn][ep]);
                    f0 = rb(f0 + rb(acc[am][bn][ep * 2 + 0]));
                    f1 = rb(f1 + rb(acc[am][bn][ep * 2 + 1]));
                    outp[am][bn][ep] = pk2(f0, f1);
                }
        if (c == 0) {
#pragma unroll
            for (int bn = 0; bn < 4; bn++) {
                float bv = rb(bias[ccol0 + bn * 16 + lcol]);
#pragma unroll
                for (int am = 0; am < 4; am++)
#pragma unroll
                    for (int ep = 0; ep < 2; ep++) {
                        float f0 = rb(up_lo(outp[am][bn][ep]) + bv);
                        float f1 = rb(up_hi(outp[am][bn][ep]) + bv);
                        outp[am][bn][ep] = pk2(f0, f1);
                    }
            }
        }
    }

#pragma unroll
    for (int bn = 0; bn < 4; bn++) {
        int col = ccol0 + bn * 16 + lcol;
#pragma unroll
        for (int am = 0; am < 4; am++) {
            int row = crow0 + am * 16 + lrow4;
            C[(size_t)(row + 0) * N + col] = up_lo(outp[am][bn][0]);
            C[(size_t)(row + 1) * N + col] = up_hi(outp[am][bn][0]);
            C[(size_t)(row + 2) * N + col] = up_lo(outp[am][bn][1]);
            C[(size_t)(row + 3) * N + col] = up_hi(outp[am][bn][1]);
        }
    }
}

// ------------------------------------------------------------------ host
extern "C" void kernel_launch(void* const* d_in, const int* in_sizes, int n_in,
                              void* d_out, int out_size, void* d_ws, size_t ws_size,
                              hipStream_t stream) {
    const float* h_x   = (const float*)d_in[0];
    const int*   tp    = (const int*)d_in[1];
    const float* z     = (const float*)d_in[2];
    const float* pe    = (const float*)d_in[3];
    const float* base0 = (const float*)d_in[4];
    const float* poly0 = (const float*)d_in[5];
    const float* rms0  = (const float*)d_in[6];
    const float* base1 = (const float*)d_in[7];
    const float* poly1 = (const float*)d_in[8];
    const float* rms1  = (const float*)d_in[9];
    float* out = (float*)d_out;

    char* ws = (char*)d_ws;
    size_t off = 0;
    bf16* wctx  = (bf16*)(ws + off); off += (size_t)HID * KCTX * 2;
    bf16* wposz = (bf16*)(ws + off); off += (size_t)HID * KPZ * 2;
    bf16* wb1   = (bf16*)(ws + off); off += (size_t)OUT1 * K1 * 2;
    float* bias0 = (float*)(ws + off); off += HID * 4;
    float* bias1 = (float*)(ws + off); off += OUT1 * 4;
    float* partial = (float*)(ws + off); off += 32 * HID * 4;
    bf16* Fctx = (bf16*)(ws + off); off += (size_t)B_SZ * KCTX * 2;
    float* ctx_part = (float*)(ws + off); off += (size_t)B_SZ * NCH * HID * 4;
    bf16* Fpos = (bf16*)(ws + off); off += (size_t)NPOS * KPOS * 2;   // 109 MB
    bf16* Fz   = (bf16*)(ws + off); off += (size_t)M_TOT * KZ * 2;    // 13.6 MB
    bf16* H0   = (bf16*)(ws + off); off += (size_t)M_TOT * HID * 2;   // 67 MB
    size_t fixed = off;

    bf16* F1 = (bf16*)(ws + off);
    size_t avail = ws_size > fixed ? ws_size - fixed : 0;
    long long chunk_ll = (long long)(avail / ((size_t)K1 * 2));
    int chunk = (int)(chunk_ll > M_TOT ? M_TOT : chunk_ll);
    chunk &= ~127;
    if (chunk < 128) chunk = 128;

    dim3 tb(32, 8);
    convert_w0<<<dim3(IN0 / 32, HID / 32, NCH), tb, 0, stream>>>(base0, poly0, wctx, wposz);
    convert_w<<<dim3(HID / 32, OUT1 / 32, NCH), tb, 0, stream>>>(base1, poly1, wb1, HID, OUT1);
    col_sum_s1<<<dim3(HID / 64, 32), dim3(64, 4), 0, stream>>>(poly0, partial, IN0, HID);
    col_sum_s2<<<HID / 256, 256, 0, stream>>>(partial, bias0, HID);
    col_sum_s1<<<dim3(OUT1 / 64, 32), dim3(64, 4), 0, stream>>>(poly1, partial, HID, OUT1);
    col_sum_s2<<<OUT1 / 256, 256, 0, stream>>>(partial, bias1, OUT1);
    build_fctx<<<8, 256, 0, stream>>>(h_x, Fctx);
    ctx_dot<<<dim3(HID / 64, NCH, B_SZ), dim3(64, 4), 0, stream>>>(Fctx, wctx, ctx_part);
    build_fpos<<<(NPOS * 128) / 256, 256, 0, stream>>>(pe, Fpos);
    build_fz<<<(M_TOT * (ZD / 8)) / 256, 256, 0, stream>>>(z, Fz);

    gemm0_k<<<(M_TOT / BM0) * (HID / BN0), 256, 0, stream>>>(
        Fpos, Fz, tp, wposz, bias0, ctx_part, (unsigned short*)H0);

    for (int m0 = 0; m0 < M_TOT; m0 += chunk) {
        int rows = (M_TOT - m0 < chunk) ? (M_TOT - m0) : chunk;
        rmsnorm_feat<<<rows, 256, 0, stream>>>(H0 + (size_t)m0 * HID, rms0, F1);
        float* o = out + (size_t)m0 * OUT1;
        gemm1_k<<<(rows / BM1) * (OUT1 / BN1), 256, 0, stream>>>(F1, wb1, bias1, o, rows);
    }
    rmsnorm_k<OUT1><<<M_TOT, 256, 0, stream>>>(out, rms1);
}

// Round 19
// 3349.376 us; speedup vs baseline: 1.6417x; 1.6417x over previous
//
#include <hip/hip_runtime.h>
#include <hip/hip_bf16.h>
#include <math.h>

#define B_SZ 8
#define NT 2048
#define M_TOT (B_SZ * NT)      // 16384
#define DM 1024
#define ZD 32
#define IN0 2080
#define HID 2048
#define OUT1 1024
#define NCH 13                 // silu + T1..T12 (T0 folded into bias)
#define PZ 1056                // pos(1024)+z(32) per chunk
#define KPZ (NCH * PZ)         // 13728
#define KCTX (NCH * DM)        // 13312
#define KPOS (NCH * DM)        // 13312
#define KZ (NCH * ZD)          // 416
#define K1 (NCH * HID)         // 26624
#define NPOS 4096
#define RMS_EPS 1e-6f

typedef __bf16 bf16;
typedef __bf16 bf16x4 __attribute__((ext_vector_type(4)));
typedef __bf16 bf16x8 __attribute__((ext_vector_type(8)));
typedef float f32x4 __attribute__((ext_vector_type(4)));

__device__ __forceinline__ void gload16(const void* g, void* l) {
    __builtin_amdgcn_global_load_lds(
        (const __attribute__((address_space(1))) void*)g,
        (__attribute__((address_space(3))) void*)l, 16, 0, 0);
}

__device__ __forceinline__ float rb(float x) { return (float)(bf16)x; }

__device__ __forceinline__ unsigned pk2(float lo, float hi) {
    return (__builtin_bit_cast(unsigned, hi) & 0xFFFF0000u) |
           (__builtin_bit_cast(unsigned, lo) >> 16);
}
__device__ __forceinline__ float up_lo(unsigned u) { return __builtin_bit_cast(float, u << 16); }
__device__ __forceinline__ float up_hi(unsigned u) { return __builtin_bit_cast(float, u & 0xFFFF0000u); }

// ------------------------------------- layer-0 weight convert, split ctx / pos+z
__global__ __launch_bounds__(256) void convert_w0(const float* __restrict__ base,
                                                  const float* __restrict__ poly,
                                                  bf16* __restrict__ wctx,
                                                  bf16* __restrict__ wposz) {
    __shared__ float tile[32][33];
    int c = blockIdx.z;
    const float* src = (c == 0) ? base : (poly + (size_t)c * IN0 * HID);
    int i0 = blockIdx.x * 32, n0 = blockIdx.y * 32;
    int tx = threadIdx.x, ty = threadIdx.y;
#pragma unroll
    for (int r = 0; r < 4; r++)
        tile[ty + r * 8][tx] = src[(size_t)(i0 + ty + r * 8) * HID + n0 + tx];
    __syncthreads();
#pragma unroll
    for (int r = 0; r < 4; r++) {
        int n = n0 + ty + r * 8;
        int i = i0 + tx;
        bf16 v = (bf16)tile[tx][ty + r * 8];
        if (i < 1024) wctx[(size_t)n * KCTX + (size_t)c * 1024 + i] = v;
        else          wposz[(size_t)n * KPZ + (size_t)c * PZ + (i - 1024)] = v;
    }
}

__global__ __launch_bounds__(256) void convert_w(const float* __restrict__ base,
                                                 const float* __restrict__ poly,
                                                 bf16* __restrict__ dst, int IN, int OUT) {
    __shared__ float tile[32][33];
    int c = blockIdx.z;
    const float* src = (c == 0) ? base : (poly + (size_t)c * IN * OUT);
    int i0 = blockIdx.x * 32, n0 = blockIdx.y * 32;
    int tx = threadIdx.x, ty = threadIdx.y;
#pragma unroll
    for (int r = 0; r < 4; r++)
        tile[ty + r * 8][tx] = src[(size_t)(i0 + ty + r * 8) * OUT + n0 + tx];
    __syncthreads();
    size_t ldd = (size_t)NCH * IN;
#pragma unroll
    for (int r = 0; r < 4; r++) {
        int n = n0 + ty + r * 8;
        int i = i0 + tx;
        dst[(size_t)n * ldd + (size_t)c * IN + i] = (bf16)tile[tx][ty + r * 8];
    }
}

// ---------------- bias[n] = f32-sum_i bf16(poly[0][i][n])
__global__ void col_sum_s1(const float* __restrict__ w, float* __restrict__ partial,
                           int IN, int OUT) {
    __shared__ float sm[4][64];
    int tx = threadIdx.x, ty = threadIdx.y;
    int n = blockIdx.x * 64 + tx;
    int s = blockIdx.y;
    float acc = 0.f;
    for (int i = 4 * s + ty; i < IN; i += 128) acc += (float)(bf16)w[(size_t)i * OUT + n];
    sm[ty][tx] = acc;
    __syncthreads();
    if (ty == 0) partial[(size_t)s * OUT + n] = sm[0][tx] + sm[1][tx] + sm[2][tx] + sm[3][tx];
}
__global__ void col_sum_s2(const float* __restrict__ partial, float* __restrict__ bias, int OUT) {
    int n = blockIdx.x * 256 + threadIdx.x;
    if (n >= OUT) return;
    float s = 0.f;
#pragma unroll
    for (int k = 0; k < 32; k++) s += partial[(size_t)k * OUT + n];
    bias[n] = s;
}

// ------------------------------------------------------------ feature build
// silu with PER-OP bf16 rounding; tanh/Chebyshev in f32 (frozen numerics path).
__device__ __forceinline__ void write_features4(bf16* __restrict__ row, int i,
                                                float4 o, int stride) {
    float x[4] = {o.x, o.y, o.z, o.w};
    bf16x4 t;
#pragma unroll
    for (int l = 0; l < 4; l++) {
        float xb = rb(x[l]);
        float e  = rb(expf(-xb));
        float d  = rb(1.f + e);
        float sg = rb(1.f / d);
        t[l] = (bf16)(xb * sg);
    }
    *(bf16x4*)&row[i] = t;
    float xs[4], Tp[4], Tc[4];
#pragma unroll
    for (int l = 0; l < 4; l++) {
        xs[l] = tanhf(x[l]);
        Tp[l] = 1.f; Tc[l] = xs[l];
        t[l] = (bf16)xs[l];
    }
    *(bf16x4*)&row[(size_t)stride + i] = t;
#pragma unroll
    for (int k = 2; k < NCH; k++) {
#pragma unroll
        for (int l = 0; l < 4; l++) {
            float Tn = 2.f * xs[l] * Tc[l] - Tp[l];
            t[l] = (bf16)Tn;
            Tp[l] = Tc[l]; Tc[l] = Tn;
        }
        *(bf16x4*)&row[(size_t)k * stride + i] = t;
    }
}

// 8-wide variant: identical per-element math, 16B stores
__device__ __forceinline__ void write_features8(bf16* __restrict__ row, int i,
                                                const float* __restrict__ x, int stride) {
    bf16x8 t;
#pragma unroll
    for (int l = 0; l < 8; l++) {
        float xb = rb(x[l]);
        float e  = rb(expf(-xb));
        float d  = rb(1.f + e);
        float sg = rb(1.f / d);
        t[l] = (bf16)(xb * sg);
    }
    *(bf16x8*)&row[i] = t;
    float xs[8], Tp[8], Tc[8];
#pragma unroll
    for (int l = 0; l < 8; l++) {
        xs[l] = tanhf(x[l]);
        Tp[l] = 1.f; Tc[l] = xs[l];
        t[l] = (bf16)xs[l];
    }
    *(bf16x8*)&row[(size_t)stride + i] = t;
#pragma unroll
    for (int k = 2; k < NCH; k++) {
#pragma unroll
        for (int l = 0; l < 8; l++) {
            float Tn = 2.f * xs[l] * Tc[l] - Tp[l];
            t[l] = (bf16)Tn;
            Tp[l] = Tc[l]; Tc[l] = Tn;
        }
        *(bf16x8*)&row[(size_t)k * stride + i] = t;
    }
}

__global__ __launch_bounds__(256) void build_fctx(const float* __restrict__ h_x,
                                                  bf16* __restrict__ Fctx) {
    int id = blockIdx.x * 256 + threadIdx.x;
    int b = id >> 8;
    int i = (id & 255) * 4;
    float4 v = *(const float4*)&h_x[((size_t)b * 128 + 127) * DM + i];
    write_features4(Fctx + (size_t)b * KCTX, i, v, DM);
}

__global__ void ctx_dot(const bf16* __restrict__ Fctx, const bf16* __restrict__ wctx,
                        float* __restrict__ ctx_part) {
    __shared__ float sm[4][64];
    int tx = threadIdx.x, ty = threadIdx.y;
    int n = blockIdx.x * 64 + tx;
    int c = blockIdx.y, b = blockIdx.z;
    const bf16* f = Fctx + ((size_t)b * NCH + c) * DM;
    const bf16* wv = wctx + (size_t)n * KCTX + (size_t)c * DM;
    float s = 0.f;
    for (int i = ty; i < DM; i += 4) s += (float)f[i] * (float)wv[i];
    sm[ty][tx] = s;
    __syncthreads();
    if (ty == 0) ctx_part[((size_t)b * NCH + c) * HID + n] = sm[0][tx] + sm[1][tx] + sm[2][tx] + sm[3][tx];
}

// pos table: 8 elements/thread, 16B stores
__global__ __launch_bounds__(256) void build_fpos(const float* __restrict__ pe,
                                                  bf16* __restrict__ Fpos) {
    int id = blockIdx.x * 256 + threadIdx.x;   // 4096 * 128
    int p = id >> 7;
    int i = (id & 127) * 8;
    float x[8];
    *(float4*)&x[0] = *(const float4*)&pe[(size_t)p * DM + i];
    *(float4*)&x[4] = *(const float4*)&pe[(size_t)p * DM + i + 4];
    write_features8(Fpos + (size_t)p * KPOS, i, x, DM);
}

// z features: 8 elements/thread (4 threads/row)
__global__ __launch_bounds__(256) void build_fz(const float* __restrict__ z,
                                                bf16* __restrict__ Fz) {
    int id = blockIdx.x * 256 + threadIdx.x;   // M_TOT * 4
    if (id >= M_TOT * (ZD / 8)) return;
    int ml = id >> 2;
    int i = (id & 3) * 8;
    float x[8];
    *(float4*)&x[0] = *(const float4*)&z[(size_t)ml * ZD + i];
    *(float4*)&x[4] = *(const float4*)&z[(size_t)ml * ZD + i + 4];
    write_features8(Fz + (size_t)ml * KZ, i, x, ZD);
}

// ---------------------------------------------- fused RMSNorm + layer-1 feature build
__global__ __launch_bounds__(256) void rmsnorm_feat(const bf16* __restrict__ H,
                                                    const float* __restrict__ scale,
                                                    bf16* __restrict__ F) {
    int row = blockIdx.x;
    int t = threadIdx.x;
    bf16x8 h = *(const bf16x8*)&H[(size_t)row * HID + t * 8];
    float f[8];
    float s = 0.f;
#pragma unroll
    for (int l = 0; l < 8; l++) { f[l] = (float)h[l]; s += f[l] * f[l]; }
#pragma unroll
    for (int o = 32; o > 0; o >>= 1) s += __shfl_down(s, o, 64);
    __shared__ float wsum[4];
    if ((t & 63) == 0) wsum[t >> 6] = s;
    __syncthreads();
    s = wsum[0] + wsum[1] + wsum[2] + wsum[3];
    float rs = rsqrtf(s * (1.0f / HID) + RMS_EPS);
    const float4* sc = (const float4*)scale;
    float4 sv0 = sc[t * 2], sv1 = sc[t * 2 + 1];
    bf16* Frow = F + (size_t)row * K1;
    float x[8];
    x[0] = f[0] * rs * sv0.x; x[1] = f[1] * rs * sv0.y;
    x[2] = f[2] * rs * sv0.z; x[3] = f[3] * rs * sv0.w;
    x[4] = f[4] * rs * sv1.x; x[5] = f[5] * rs * sv1.y;
    x[6] = f[6] * rs * sv1.z; x[7] = f[7] * rs * sv1.w;
    write_features8(Frow, t * 8, x, HID);
}

// ------------------------------------------------------------------ final RMSNorm (in place)
template <int N>
__global__ __launch_bounds__(256) void rmsnorm_k(float* __restrict__ H,
                                                 const float* __restrict__ scale) {
    constexpr int VPT = N / (4 * 256);
    int row = blockIdx.x;
    float4* p = (float4*)(H + (size_t)row * N);
    const float4* sc = (const float4*)scale;
    float4 v[VPT];
    float s = 0.f;
#pragma unroll
    for (int j = 0; j < VPT; j++) {
        v[j] = p[threadIdx.x + j * 256];
        s += v[j].x * v[j].x + v[j].y * v[j].y + v[j].z * v[j].z + v[j].w * v[j].w;
    }
#pragma unroll
    for (int o = 32; o > 0; o >>= 1) s += __shfl_down(s, o, 64);
    __shared__ float wsum[4];
    if ((threadIdx.x & 63) == 0) wsum[threadIdx.x >> 6] = s;
    __syncthreads();
    s = wsum[0] + wsum[1] + wsum[2] + wsum[3];
    float rs = rsqrtf(s * (1.0f / N) + RMS_EPS);
#pragma unroll
    for (int j = 0; j < VPT; j++) {
        float4 sv = sc[threadIdx.x + j * 256];
        float4 o_;
        o_.x = v[j].x * rs * sv.x;
        o_.y = v[j].y * rs * sv.y;
        o_.z = v[j].z * rs * sv.z;
        o_.w = v[j].w * rs * sv.w;
        p[threadIdx.x + j * 256] = o_;
    }
}

// ============================ GEMM0: gather-A, BM128 x BN128, 256 thr, BK=64 (+32 z-step)
// R14-proven: swizzled LDS; gload_lds dest linear, source granule permuted; GROUP_M=32.
// __launch_bounds__(256,4) — (256,5) measured BAD (VGPR cap -> 48 regs, MfmaUtil 16%).
#define BM0 128
#define BN0 128
#define GROUP_M 32

__global__ __launch_bounds__(256, 4) void gemm0_k(const bf16* __restrict__ Fpos,
                                                  const bf16* __restrict__ Fz,
                                                  const int* __restrict__ tp,
                                                  const bf16* __restrict__ Bt,
                                                  const float* __restrict__ bias,
                                                  const float* __restrict__ ctxp,
                                                  unsigned short* __restrict__ C) {
    __shared__ __align__(16) bf16 As[BM0 * 64];   // 16 KB
    __shared__ __align__(16) bf16 Bs[BN0 * 64];   // 16 KB

    const int N = HID;
    const int nbm = M_TOT / BM0, nbn = N / BN0;   // 128 x 16
    int pid = blockIdx.x;
    int width = GROUP_M * nbn;
    int group_id = pid / width;
    int first_m = group_id * GROUP_M;
    int gsz = min(nbm - first_m, GROUP_M);
    int mb = first_m + (pid % width) % gsz;
    int nb = (pid % width) / gsz;

    int t = threadIdx.x;
    int lane = t & 63, wid = t >> 6;
    int wm = wid >> 1, wn = wid & 1;              // 2x2 waves, 64x64 each

    const unsigned colx = (unsigned)(((t & 7) ^ ((t >> 3) & 7)) * 8);
    const unsigned colz = (unsigned)(((t & 3) ^ ((t >> 2) & 3)) * 8);
    unsigned offA[4];
#pragma unroll
    for (int i = 0; i < 4; i++)
        offA[i] = (unsigned)tp[mb * BM0 + (t >> 3) + i * 32] * KPOS + colx;
    unsigned offZA[2];
#pragma unroll
    for (int i = 0; i < 2; i++)
        offZA[i] = (unsigned)(mb * BM0 + (t >> 2) + i * 64) * KZ + colz;
    const unsigned offB  = (unsigned)(nb * BN0 + (t >> 3)) * KPZ + colx;
    const unsigned offBz = (unsigned)(nb * BN0 + (t >> 2)) * KPZ + colz + 1024u;

    const int arow = wm * 64 + (lane & 15);
    const int brow = wn * 64 + (lane & 15);
    const int kqo = (lane >> 4) * 8;

    const int lcol = lane & 15, lrow4 = (lane >> 4) * 4;
    const int crow0 = mb * BM0 + wm * 64;
    const int ccol0 = nb * BN0 + wn * 64;
    const int b = (mb * BM0) >> 11;

    unsigned outp[4][4][2] = {};

    for (int c = 0; c < NCH; c++) {
        f32x4 acc[4][4];
        {
            const float* cp = ctxp + ((size_t)b * NCH + c) * N;
#pragma unroll
            for (int bn = 0; bn < 4; bn++) {
                float cv = cp[ccol0 + bn * 16 + lcol];
#pragma unroll
                for (int am = 0; am < 4; am++) acc[am][bn] = (f32x4){cv, cv, cv, cv};
            }
        }
        // pos part: 16 steps of BK=64
        for (int ks = 0; ks < 1024; ks += 64) {
            unsigned co = (unsigned)c * 1024u + ks;
#pragma unroll
            for (int i = 0; i < 4; i++)
                gload16(Fpos + offA[i] + co, (char*)As + (t + i * 256) * 16);
            unsigned cb = (unsigned)c * PZ + ks;
#pragma unroll
            for (int i = 0; i < 4; i++)
                gload16(Bt + offB + (unsigned)i * (32u * KPZ) + cb, (char*)Bs + (t + i * 256) * 16);
            __syncthreads();
#pragma unroll
            for (int h = 0; h < 2; h++) {
                bf16x8 af[4], bfr[4];
#pragma unroll
                for (int am = 0; am < 4; am++) {
                    int L = (arow + am * 16) * 128 + h * 64 + kqo * 2;
                    int P = L ^ (((L >> 7) & 7) << 4);
                    af[am] = *(const bf16x8*)((const char*)As + P);
                }
#pragma unroll
                for (int bn = 0; bn < 4; bn++) {
                    int L = (brow + bn * 16) * 128 + h * 64 + kqo * 2;
                    int P = L ^ (((L >> 7) & 7) << 4);
                    bfr[bn] = *(const bf16x8*)((const char*)Bs + P);
                }
#pragma unroll
                for (int am = 0; am < 4; am++)
#pragma unroll
                    for (int bn = 0; bn < 4; bn++)
                        acc[am][bn] = __builtin_amdgcn_mfma_f32_16x16x32_bf16(af[am], bfr[bn], acc[am][bn], 0, 0, 0);
            }
            __syncthreads();
        }
        // z-step (BK=32), 64B rows
        {
#pragma unroll
            for (int i = 0; i < 2; i++)
                gload16(Fz + offZA[i] + (unsigned)c * 32u, (char*)As + (t + i * 256) * 16);
            unsigned cb = (unsigned)c * PZ;
#pragma unroll
            for (int i = 0; i < 2; i++)
                gload16(Bt + offBz + (unsigned)i * (64u * KPZ) + cb, (char*)Bs + (t + i * 256) * 16);
            __syncthreads();
            bf16x8 af[4], bfr[4];
#pragma unroll
            for (int am = 0; am < 4; am++) {
                int L = (arow + am * 16) * 64 + kqo * 2;
                int P = L ^ (((L >> 6) & 3) << 4);
                af[am] = *(const bf16x8*)((const char*)As + P);
            }
#pragma unroll
            for (int bn = 0; bn < 4; bn++) {
                int L = (brow + bn * 16) * 64 + kqo * 2;
                int P = L ^ (((L >> 6) & 3) << 4);
                bfr[bn] = *(const bf16x8*)((const char*)Bs + P);
            }
#pragma unroll
            for (int am = 0; am < 4; am++)
#pragma unroll
                for (int bn = 0; bn < 4; bn++)
                    acc[am][bn] = __builtin_amdgcn_mfma_f32_16x16x32_bf16(af[am], bfr[bn], acc[am][bn], 0, 0, 0);
            __syncthreads();
        }
        // fold
#pragma unroll
        for (int am = 0; am < 4; am++)
#pragma unroll
            for (int bn = 0; bn < 4; bn++)
#pragma unroll
                for (int ep = 0; ep < 2; ep++) {
                    float f0 = up_lo(outp[am][bn][ep]);
                    float f1 = up_hi(outp[am][bn][ep]);
                    f0 = rb(f0 + rb(acc[am][bn][ep * 2 + 0]));
                    f1 = rb(f1 + rb(acc[am][bn][ep * 2 + 1]));
                    outp[am][bn][ep] = pk2(f0, f1);
                }
        if (c == 0) {
#pragma unroll
            for (int bn = 0; bn < 4; bn++) {
                float bv = rb(bias[ccol0 + bn * 16 + lcol]);
#pragma unroll
                for (int am = 0; am < 4; am++)
#pragma unroll
                    for (int ep = 0; ep < 2; ep++) {
                        float f0 = rb(up_lo(outp[am][bn][ep]) + bv);
                        float f1 = rb(up_hi(outp[am][bn][ep]) + bv);
                        outp[am][bn][ep] = pk2(f0, f1);
                    }
            }
        }
    }

#pragma unroll
    for (int bn = 0; bn < 4; bn++) {
        int col = ccol0 + bn * 16 + lcol;
#pragma unroll
        for (int am = 0; am < 4; am++) {
            int row = crow0 + am * 16 + lrow4;
            C[(size_t)(row + 0) * N + col] = (unsigned short)(outp[am][bn][0] & 0xFFFFu);
            C[(size_t)(row + 1) * N + col] = (unsigned short)(outp[am][bn][0] >> 16);
            C[(size_t)(row + 2) * N + col] = (unsigned short)(outp[am][bn][1] & 0xFFFFu);
            C[(size_t)(row + 3) * N + col] = (unsigned short)(outp[am][bn][1] >> 16);
        }
    }
}

// ============================ GEMM1: dense-A, BM128 x BN128, 256 thr, BK=64 (R14-proven)
#define BM1 128
#define BN1 128

__global__ __launch_bounds__(256, 4) void gemm1_k(const bf16* __restrict__ A,
                                                  const bf16* __restrict__ Bt,
                                                  const float* __restrict__ bias,
                                                  float* __restrict__ C,
                                                  int Mrows) {
    __shared__ __align__(16) bf16 As[BM1 * 64];   // 16 KB
    __shared__ __align__(16) bf16 Bs[BN1 * 64];   // 16 KB

    const int N = OUT1, IN = HID, K = K1;
    const int nbm = Mrows / BM1, nbn = N / BN1;
    int pid = blockIdx.x;
    int width = GROUP_M * nbn;
    int group_id = pid / width;
    int first_m = group_id * GROUP_M;
    int gsz = min(nbm - first_m, GROUP_M);
    int mb = first_m + (pid % width) % gsz;
    int nb = (pid % width) / gsz;

    int t = threadIdx.x;
    int lane = t & 63, wid = t >> 6;
    int wm = wid >> 1, wn = wid & 1;              // 2x2 waves, 64x64 each

    const unsigned colx = (unsigned)(((t & 7) ^ ((t >> 3) & 7)) * 8);
    const unsigned offA = (unsigned)(mb * BM1 + (t >> 3)) * (unsigned)K + colx;
    const unsigned offB = (unsigned)(nb * BN1 + (t >> 3)) * (unsigned)K + colx;

    const int arow = wm * 64 + (lane & 15);
    const int brow = wn * 64 + (lane & 15);
    const int kqo = (lane >> 4) * 8;

    const int lcol = lane & 15, lrow4 = (lane >> 4) * 4;
    const int crow0 = mb * BM1 + wm * 64;
    const int ccol0 = nb * BN1 + wn * 64;

    unsigned outp[4][4][2] = {};

    for (int c = 0; c < NCH; c++) {
        f32x4 acc[4][4] = {};
        for (int ks = 0; ks < IN; ks += 64) {
            unsigned co = (unsigned)c * (unsigned)IN + ks;
#pragma unroll
            for (int i = 0; i < 4; i++) {
                gload16(A + offA + (unsigned)i * (32u * (unsigned)K) + co, (char*)As + (t + i * 256) * 16);
                gload16(Bt + offB + (unsigned)i * (32u * (unsigned)K) + co, (char*)Bs + (t + i * 256) * 16);
            }
            __syncthreads();
#pragma unroll
            for (int h = 0; h < 2; h++) {
                bf16x8 af[4], bfr[4];
#pragma unroll
                for (int am = 0; am < 4; am++) {
                    int L = (arow + am * 16) * 128 + h * 64 + kqo * 2;
                    int P = L ^ (((L >> 7) & 7) << 4);
                    af[am] = *(const bf16x8*)((const char*)As + P);
                }
#pragma unroll
                for (int bn = 0; bn < 4; bn++) {
                    int L = (brow + bn * 16) * 128 + h * 64 + kqo * 2;
                    int P = L ^ (((L >> 7) & 7) << 4);
                    bfr[bn] = *(const bf16x8*)((const char*)Bs + P);
                }
#pragma unroll
                for (int am = 0; am < 4; am++)
#pragma unroll
                    for (int bn = 0; bn < 4; bn++)
                        acc[am][bn] = __builtin_amdgcn_mfma_f32_16x16x32_bf16(af[am], bfr[bn], acc[am][bn], 0, 0, 0);
            }
            __syncthreads();
        }
#pragma unroll
        for (int am = 0; am < 4; am++)
#pragma unroll
            for (int bn = 0; bn < 4; bn++)
#pragma unroll
                for (int ep = 0; ep < 2; ep++) {
                    float f0 = up_lo(outp[am][bn][ep]);
                    float f1 = up_hi(outp[am][bn][ep]);
                    f0 = rb(f0 + rb(acc[am][bn][ep * 2 + 0]));
                    f1 = rb(f1 + rb(acc[am][bn][ep * 2 + 1]));
                    outp[am][bn][ep] = pk2(f0, f1);
                }
        if (c == 0) {
#pragma unroll
            for (int bn = 0; bn < 4; bn++) {
                float bv = rb(bias[ccol0 + bn * 16 + lcol]);
#pragma unroll
                for (int am = 0; am < 4; am++)
#pragma unroll
                    for (int ep = 0; ep < 2; ep++) {
                        float f0 = rb(up_lo(outp[am][bn][ep]) + bv);
                        float f1 = rb(up_hi(outp[am][bn][ep]) + bv);
                        outp[am][bn][ep] = pk2(f0, f1);
                    }
            }
        }
    }

#pragma unroll
    for (int bn = 0; bn < 4; bn++) {
        int col = ccol0 + bn * 16 + lcol;
#pragma unroll
        for (int am = 0; am < 4; am++) {
            int row = crow0 + am * 16 + lrow4;
            C[(size_t)(row + 0) * N + col] = up_lo(outp[am][bn][0]);
            C[(size_t)(row + 1) * N + col] = up_hi(outp[am][bn][0]);
            C[(size_t)(row + 2) * N + col] = up_lo(outp[am][bn][1]);
            C[(size_t)(row + 3) * N + col] = up_hi(outp[am][bn][1]);
        }
    }
}

// ------------------------------------------------------------------ host
extern "C" void kernel_launch(void* const* d_in, const int* in_sizes, int n_in,
                              void* d_out, int out_size, void* d_ws, size_t ws_size,
                              hipStream_t stream) {
    const float* h_x   = (const float*)d_in[0];
    const int*   tp    = (const int*)d_in[1];
    const float* z     = (const float*)d_in[2];
    const float* pe    = (const float*)d_in[3];
    const float* base0 = (const float*)d_in[4];
    const float* poly0 = (const float*)d_in[5];
    const float* rms0  = (const float*)d_in[6];
    const float* base1 = (const float*)d_in[7];
    const float* poly1 = (const float*)d_in[8];
    const float* rms1  = (const float*)d_in[9];
    float* out = (float*)d_out;

    char* ws = (char*)d_ws;
    size_t off = 0;
    bf16* wctx  = (bf16*)(ws + off); off += (size_t)HID * KCTX * 2;
    bf16* wposz = (bf16*)(ws + off); off += (size_t)HID * KPZ * 2;
    bf16* wb1   = (bf16*)(ws + off); off += (size_t)OUT1 * K1 * 2;
    float* bias0 = (float*)(ws + off); off += HID * 4;
    float* bias1 = (float*)(ws + off); off += OUT1 * 4;
    float* partial = (float*)(ws + off); off += 32 * HID * 4;
    bf16* Fctx = (bf16*)(ws + off); off += (size_t)B_SZ * KCTX * 2;
    float* ctx_part = (float*)(ws + off); off += (size_t)B_SZ * NCH * HID * 4;
    bf16* Fpos = (bf16*)(ws + off); off += (size_t)NPOS * KPOS * 2;   // 109 MB
    bf16* Fz   = (bf16*)(ws + off); off += (size_t)M_TOT * KZ * 2;    // 13.6 MB
    bf16* H0   = (bf16*)(ws + off); off += (size_t)M_TOT * HID * 2;   // 67 MB
    size_t fixed = off;

    bf16* F1 = (bf16*)(ws + off);
    size_t avail = ws_size > fixed ? ws_size - fixed : 0;
    long long chunk_ll = (long long)(avail / ((size_t)K1 * 2));
    int chunk = (int)(chunk_ll > M_TOT ? M_TOT : chunk_ll);
    chunk &= ~127;
    if (chunk < 128) chunk = 128;

    dim3 tb(32, 8);
    convert_w0<<<dim3(IN0 / 32, HID / 32, NCH), tb, 0, stream>>>(base0, poly0, wctx, wposz);
    convert_w<<<dim3(HID / 32, OUT1 / 32, NCH), tb, 0, stream>>>(base1, poly1, wb1, HID, OUT1);
    col_sum_s1<<<dim3(HID / 64, 32), dim3(64, 4), 0, stream>>>(poly0, partial, IN0, HID);
    col_sum_s2<<<HID / 256, 256, 0, stream>>>(partial, bias0, HID);
    col_sum_s1<<<dim3(OUT1 / 64, 32), dim3(64, 4), 0, stream>>>(poly1, partial, HID, OUT1);
    col_sum_s2<<<OUT1 / 256, 256, 0, stream>>>(partial, bias1, OUT1);
    build_fctx<<<8, 256, 0, stream>>>(h_x, Fctx);
    ctx_dot<<<dim3(HID / 64, NCH, B_SZ), dim3(64, 4), 0, stream>>>(Fctx, wctx, ctx_part);
    build_fpos<<<(NPOS * 128) / 256, 256, 0, stream>>>(pe, Fpos);
    build_fz<<<(M_TOT * (ZD / 8)) / 256, 256, 0, stream>>>(z, Fz);

    gemm0_k<<<(M_TOT / BM0) * (HID / BN0), 256, 0, stream>>>(
        Fpos, Fz, tp, wposz, bias0, ctx_part, (unsigned short*)H0);

    for (int m0 = 0; m0 < M_TOT; m0 += chunk) {
        int rows = (M_TOT - m0 < chunk) ? (M_TOT - m0) : chunk;
        rmsnorm_feat<<<rows, 256, 0, stream>>>(H0 + (size_t)m0 * HID, rms0, F1);
        float* o = out + (size_t)m0 * OUT1;
        gemm1_k<<<(rows / BM1) * (OUT1 / BN1), 256, 0, stream>>>(F1, wb1, bias1, o, rows);
    }
    rmsnorm_k<OUT1><<<M_TOT, 256, 0, stream>>>(out, rms1);
}

// Round 20
// 3330.511 us; speedup vs baseline: 1.6510x; 1.0057x over previous
//
#include <hip/hip_runtime.h>
#include <hip/hip_bf16.h>
#include <math.h>

#define B_SZ 8
#define NT 2048
#define M_TOT (B_SZ * NT)      // 16384
#define DM 1024
#define ZD 32
#define IN0 2080
#define HID 2048
#define OUT1 1024
#define NCH 13                 // silu + T1..T12 (T0 folded into bias)
#define PZ 1056                // pos(1024)+z(32) per chunk
#define KPZ (NCH * PZ)         // 13728
#define KCTX (NCH * DM)        // 13312
#define KZ (NCH * ZD)          // 416
#define K1 (NCH * HID)         // 26624
#define NPOS 4096
#define RMS_EPS 1e-6f

typedef __bf16 bf16;
typedef __bf16 bf16x4 __attribute__((ext_vector_type(4)));
typedef __bf16 bf16x8 __attribute__((ext_vector_type(8)));
typedef float f32x4 __attribute__((ext_vector_type(4)));

__device__ __forceinline__ void gload16(const void* g, void* l) {
    __builtin_amdgcn_global_load_lds(
        (const __attribute__((address_space(1))) void*)g,
        (__attribute__((address_space(3))) void*)l, 16, 0, 0);
}

__device__ __forceinline__ float rb(float x) { return (float)(bf16)x; }

__device__ __forceinline__ unsigned pk2(float lo, float hi) {
    return (__builtin_bit_cast(unsigned, hi) & 0xFFFF0000u) |
           (__builtin_bit_cast(unsigned, lo) >> 16);
}
__device__ __forceinline__ float up_lo(unsigned u) { return __builtin_bit_cast(float, u << 16); }
__device__ __forceinline__ float up_hi(unsigned u) { return __builtin_bit_cast(float, u & 0xFFFF0000u); }

// ------------------------------------- layer-0 weight convert, split ctx / pos+z
__global__ __launch_bounds__(256) void convert_w0(const float* __restrict__ base,
                                                  const float* __restrict__ poly,
                                                  bf16* __restrict__ wctx,
                                                  bf16* __restrict__ wposz) {
    __shared__ float tile[32][33];
    int c = blockIdx.z;
    const float* src = (c == 0) ? base : (poly + (size_t)c * IN0 * HID);
    int i0 = blockIdx.x * 32, n0 = blockIdx.y * 32;
    int tx = threadIdx.x, ty = threadIdx.y;
#pragma unroll
    for (int r = 0; r < 4; r++)
        tile[ty + r * 8][tx] = src[(size_t)(i0 + ty + r * 8) * HID + n0 + tx];
    __syncthreads();
#pragma unroll
    for (int r = 0; r < 4; r++) {
        int n = n0 + ty + r * 8;
        int i = i0 + tx;
        bf16 v = (bf16)tile[tx][ty + r * 8];
        if (i < 1024) wctx[(size_t)n * KCTX + (size_t)c * 1024 + i] = v;
        else          wposz[(size_t)n * KPZ + (size_t)c * PZ + (i - 1024)] = v;
    }
}

__global__ __launch_bounds__(256) void convert_w(const float* __restrict__ base,
                                                 const float* __restrict__ poly,
                                                 bf16* __restrict__ dst, int IN, int OUT) {
    __shared__ float tile[32][33];
    int c = blockIdx.z;
    const float* src = (c == 0) ? base : (poly + (size_t)c * IN * OUT);
    int i0 = blockIdx.x * 32, n0 = blockIdx.y * 32;
    int tx = threadIdx.x, ty = threadIdx.y;
#pragma unroll
    for (int r = 0; r < 4; r++)
        tile[ty + r * 8][tx] = src[(size_t)(i0 + ty + r * 8) * OUT + n0 + tx];
    __syncthreads();
    size_t ldd = (size_t)NCH * IN;
#pragma unroll
    for (int r = 0; r < 4; r++) {
        int n = n0 + ty + r * 8;
        int i = i0 + tx;
        dst[(size_t)n * ldd + (size_t)c * IN + i] = (bf16)tile[tx][ty + r * 8];
    }
}

// ---------------- bias[n] = f32-sum_i bf16(poly[0][i][n])
__global__ void col_sum_s1(const float* __restrict__ w, float* __restrict__ partial,
                           int IN, int OUT) {
    __shared__ float sm[4][64];
    int tx = threadIdx.x, ty = threadIdx.y;
    int n = blockIdx.x * 64 + tx;
    int s = blockIdx.y;
    float acc = 0.f;
    for (int i = 4 * s + ty; i < IN; i += 128) acc += (float)(bf16)w[(size_t)i * OUT + n];
    sm[ty][tx] = acc;
    __syncthreads();
    if (ty == 0) partial[(size_t)s * OUT + n] = sm[0][tx] + sm[1][tx] + sm[2][tx] + sm[3][tx];
}
__global__ void col_sum_s2(const float* __restrict__ partial, float* __restrict__ bias, int OUT) {
    int n = blockIdx.x * 256 + threadIdx.x;
    if (n >= OUT) return;
    float s = 0.f;
#pragma unroll
    for (int k = 0; k < 32; k++) s += partial[(size_t)k * OUT + n];
    bias[n] = s;
}

// ------------------------------------------------------------ feature build
// silu with PER-OP bf16 rounding; tanh/Chebyshev in f32 (frozen numerics path).
__device__ __forceinline__ void write_features4(bf16* __restrict__ row, int i,
                                                float4 o, int stride) {
    float x[4] = {o.x, o.y, o.z, o.w};
    bf16x4 t;
#pragma unroll
    for (int l = 0; l < 4; l++) {
        float xb = rb(x[l]);
        float e  = rb(expf(-xb));
        float d  = rb(1.f + e);
        float sg = rb(1.f / d);
        t[l] = (bf16)(xb * sg);
    }
    *(bf16x4*)&row[i] = t;
    float xs[4], Tp[4], Tc[4];
#pragma unroll
    for (int l = 0; l < 4; l++) {
        xs[l] = tanhf(x[l]);
        Tp[l] = 1.f; Tc[l] = xs[l];
        t[l] = (bf16)xs[l];
    }
    *(bf16x4*)&row[(size_t)stride + i] = t;
#pragma unroll
    for (int k = 2; k < NCH; k++) {
#pragma unroll
        for (int l = 0; l < 4; l++) {
            float Tn = 2.f * xs[l] * Tc[l] - Tp[l];
            t[l] = (bf16)Tn;
            Tp[l] = Tc[l]; Tc[l] = Tn;
        }
        *(bf16x4*)&row[(size_t)k * stride + i] = t;
    }
}

// 8-wide variant: identical per-element math, 16B stores; stride = chunk-slab stride
__device__ __forceinline__ void write_features8(bf16* __restrict__ row, int i,
                                                const float* __restrict__ x, int stride) {
    bf16x8 t;
#pragma unroll
    for (int l = 0; l < 8; l++) {
        float xb = rb(x[l]);
        float e  = rb(expf(-xb));
        float d  = rb(1.f + e);
        float sg = rb(1.f / d);
        t[l] = (bf16)(xb * sg);
    }
    *(bf16x8*)&row[i] = t;
    float xs[8], Tp[8], Tc[8];
#pragma unroll
    for (int l = 0; l < 8; l++) {
        xs[l] = tanhf(x[l]);
        Tp[l] = 1.f; Tc[l] = xs[l];
        t[l] = (bf16)xs[l];
    }
    *(bf16x8*)&row[(size_t)stride + i] = t;
#pragma unroll
    for (int k = 2; k < NCH; k++) {
#pragma unroll
        for (int l = 0; l < 8; l++) {
            float Tn = 2.f * xs[l] * Tc[l] - Tp[l];
            t[l] = (bf16)Tn;
            Tp[l] = Tc[l]; Tc[l] = Tn;
        }
        *(bf16x8*)&row[(size_t)k * stride + i] = t;
    }
}

__global__ __launch_bounds__(256) void build_fctx(const float* __restrict__ h_x,
                                                  bf16* __restrict__ Fctx) {
    int id = blockIdx.x * 256 + threadIdx.x;
    int b = id >> 8;
    int i = (id & 255) * 4;
    float4 v = *(const float4*)&h_x[((size_t)b * 128 + 127) * DM + i];
    write_features4(Fctx + (size_t)b * KCTX, i, v, DM);
}

__global__ void ctx_dot(const bf16* __restrict__ Fctx, const bf16* __restrict__ wctx,
                        float* __restrict__ ctx_part) {
    __shared__ float sm[4][64];
    int tx = threadIdx.x, ty = threadIdx.y;
    int n = blockIdx.x * 64 + tx;
    int c = blockIdx.y, b = blockIdx.z;
    const bf16* f = Fctx + ((size_t)b * NCH + c) * DM;
    const bf16* wv = wctx + (size_t)n * KCTX + (size_t)c * DM;
    float s = 0.f;
    for (int i = ty; i < DM; i += 4) s += (float)f[i] * (float)wv[i];
    sm[ty][tx] = s;
    __syncthreads();
    if (ty == 0) ctx_part[((size_t)b * NCH + c) * HID + n] = sm[0][tx] + sm[1][tx] + sm[2][tx] + sm[3][tx];
}

// pos table, SLAB-MAJOR: Fpos[c][p][1024]; slab stride NPOS*1024 elements
__global__ __launch_bounds__(256) void build_fpos(const float* __restrict__ pe,
                                                  bf16* __restrict__ Fpos) {
    int id = blockIdx.x * 256 + threadIdx.x;   // 4096 * 128
    int p = id >> 7;
    int i = (id & 127) * 8;
    float x[8];
    *(float4*)&x[0] = *(const float4*)&pe[(size_t)p * DM + i];
    *(float4*)&x[4] = *(const float4*)&pe[(size_t)p * DM + i + 4];
    write_features8(Fpos + (size_t)p * 1024, i, x, NPOS * 1024);
}

// z features, SLAB-MAJOR: Fz[c][m][32]; slab stride M_TOT*32
__global__ __launch_bounds__(256) void build_fz(const float* __restrict__ z,
                                                bf16* __restrict__ Fz) {
    int id = blockIdx.x * 256 + threadIdx.x;   // M_TOT * 4
    if (id >= M_TOT * (ZD / 8)) return;
    int ml = id >> 2;
    int i = (id & 3) * 8;
    float x[8];
    *(float4*)&x[0] = *(const float4*)&z[(size_t)ml * ZD + i];
    *(float4*)&x[4] = *(const float4*)&z[(size_t)ml * ZD + i + 4];
    write_features8(Fz + (size_t)ml * ZD, i, x, M_TOT * ZD);
}

// ---------------------------------------------- fused RMSNorm + layer-1 feature build
// SLAB-MAJOR F1: F[c][row][2048]; slab stride passed (chunk*HID)
__global__ __launch_bounds__(256) void rmsnorm_feat(const bf16* __restrict__ H,
                                                    const float* __restrict__ scale,
                                                    bf16* __restrict__ F, int slab) {
    int row = blockIdx.x;
    int t = threadIdx.x;
    bf16x8 h = *(const bf16x8*)&H[(size_t)row * HID + t * 8];
    float f[8];
    float s = 0.f;
#pragma unroll
    for (int l = 0; l < 8; l++) { f[l] = (float)h[l]; s += f[l] * f[l]; }
#pragma unroll
    for (int o = 32; o > 0; o >>= 1) s += __shfl_down(s, o, 64);
    __shared__ float wsum[4];
    if ((t & 63) == 0) wsum[t >> 6] = s;
    __syncthreads();
    s = wsum[0] + wsum[1] + wsum[2] + wsum[3];
    float rs = rsqrtf(s * (1.0f / HID) + RMS_EPS);
    const float4* sc = (const float4*)scale;
    float4 sv0 = sc[t * 2], sv1 = sc[t * 2 + 1];
    bf16* Frow = F + (size_t)row * HID;
    float x[8];
    x[0] = f[0] * rs * sv0.x; x[1] = f[1] * rs * sv0.y;
    x[2] = f[2] * rs * sv0.z; x[3] = f[3] * rs * sv0.w;
    x[4] = f[4] * rs * sv1.x; x[5] = f[5] * rs * sv1.y;
    x[6] = f[6] * rs * sv1.z; x[7] = f[7] * rs * sv1.w;
    write_features8(Frow, t * 8, x, slab);
}

// ------------------------------------------------------------------ final RMSNorm (in place)
template <int N>
__global__ __launch_bounds__(256) void rmsnorm_k(float* __restrict__ H,
                                                 const float* __restrict__ scale) {
    constexpr int VPT = N / (4 * 256);
    int row = blockIdx.x;
    float4* p = (float4*)(H + (size_t)row * N);
    const float4* sc = (const float4*)scale;
    float4 v[VPT];
    float s = 0.f;
#pragma unroll
    for (int j = 0; j < VPT; j++) {
        v[j] = p[threadIdx.x + j * 256];
        s += v[j].x * v[j].x + v[j].y * v[j].y + v[j].z * v[j].z + v[j].w * v[j].w;
    }
#pragma unroll
    for (int o = 32; o > 0; o >>= 1) s += __shfl_down(s, o, 64);
    __shared__ float wsum[4];
    if ((threadIdx.x & 63) == 0) wsum[threadIdx.x >> 6] = s;
    __syncthreads();
    s = wsum[0] + wsum[1] + wsum[2] + wsum[3];
    float rs = rsqrtf(s * (1.0f / N) + RMS_EPS);
#pragma unroll
    for (int j = 0; j < VPT; j++) {
        float4 sv = sc[threadIdx.x + j * 256];
        float4 o_;
        o_.x = v[j].x * rs * sv.x;
        o_.y = v[j].y * rs * sv.y;
        o_.z = v[j].z * rs * sv.z;
        o_.w = v[j].w * rs * sv.w;
        p[threadIdx.x + j * 256] = o_;
    }
}

// ============================ GEMM0: gather-A (slab Fpos/Fz), BM128 x BN128, 256 thr
// R14-proven loop; swizzled LDS; gload_lds dest linear, source granule permuted.
#define BM0 128
#define BN0 128
#define GROUP_M 32

__global__ __launch_bounds__(256, 4) void gemm0_k(const bf16* __restrict__ Fpos,
                                                  const bf16* __restrict__ Fz,
                                                  const int* __restrict__ tp,
                                                  const bf16* __restrict__ Bt,
                                                  const float* __restrict__ bias,
                                                  const float* __restrict__ ctxp,
                                                  unsigned short* __restrict__ C) {
    __shared__ __align__(16) bf16 As[BM0 * 64];   // 16 KB
    __shared__ __align__(16) bf16 Bs[BN0 * 64];   // 16 KB

    const int N = HID;
    const int nbm = M_TOT / BM0, nbn = N / BN0;   // 128 x 16
    int pid = blockIdx.x;
    int width = GROUP_M * nbn;
    int group_id = pid / width;
    int first_m = group_id * GROUP_M;
    int gsz = min(nbm - first_m, GROUP_M);
    int mb = first_m + (pid % width) % gsz;
    int nb = (pid % width) / gsz;

    int t = threadIdx.x;
    int lane = t & 63, wid = t >> 6;
    int wm = wid >> 1, wn = wid & 1;              // 2x2 waves, 64x64 each

    const unsigned colx = (unsigned)(((t & 7) ^ ((t >> 3) & 7)) * 8);
    const unsigned colz = (unsigned)(((t & 3) ^ ((t >> 2) & 3)) * 8);
    unsigned offA[4];                              // slab-local: p*1024 + colx
#pragma unroll
    for (int i = 0; i < 4; i++)
        offA[i] = (unsigned)tp[mb * BM0 + (t >> 3) + i * 32] * 1024u + colx;
    unsigned offZA[2];                             // slab-local: m*32 + colz
#pragma unroll
    for (int i = 0; i < 2; i++)
        offZA[i] = (unsigned)(mb * BM0 + (t >> 2) + i * 64) * (unsigned)ZD + colz;
    const unsigned offB  = (unsigned)(nb * BN0 + (t >> 3)) * KPZ + colx;
    const unsigned offBz = (unsigned)(nb * BN0 + (t >> 2)) * KPZ + colz + 1024u;

    const int arow = wm * 64 + (lane & 15);
    const int brow = wn * 64 + (lane & 15);
    const int kqo = (lane >> 4) * 8;

    const int lcol = lane & 15, lrow4 = (lane >> 4) * 4;
    const int crow0 = mb * BM0 + wm * 64;
    const int ccol0 = nb * BN0 + wn * 64;
    const int b = (mb * BM0) >> 11;

    unsigned outp[4][4][2] = {};

    for (int c = 0; c < NCH; c++) {
        f32x4 acc[4][4];
        {
            const float* cp = ctxp + ((size_t)b * NCH + c) * N;
#pragma unroll
            for (int bn = 0; bn < 4; bn++) {
                float cv = cp[ccol0 + bn * 16 + lcol];
#pragma unroll
                for (int am = 0; am < 4; am++) acc[am][bn] = (f32x4){cv, cv, cv, cv};
            }
        }
        const unsigned slabA = (unsigned)c * (NPOS * 1024u);
        // pos part: 16 steps of BK=64
        for (int ks = 0; ks < 1024; ks += 64) {
#pragma unroll
            for (int i = 0; i < 4; i++)
                gload16(Fpos + slabA + offA[i] + ks, (char*)As + (t + i * 256) * 16);
            unsigned cb = (unsigned)c * PZ + ks;
#pragma unroll
            for (int i = 0; i < 4; i++)
                gload16(Bt + offB + (unsigned)i * (32u * KPZ) + cb, (char*)Bs + (t + i * 256) * 16);
            __syncthreads();
#pragma unroll
            for (int h = 0; h < 2; h++) {
                bf16x8 af[4], bfr[4];
#pragma unroll
                for (int am = 0; am < 4; am++) {
                    int L = (arow + am * 16) * 128 + h * 64 + kqo * 2;
                    int P = L ^ (((L >> 7) & 7) << 4);
                    af[am] = *(const bf16x8*)((const char*)As + P);
                }
#pragma unroll
                for (int bn = 0; bn < 4; bn++) {
                    int L = (brow + bn * 16) * 128 + h * 64 + kqo * 2;
                    int P = L ^ (((L >> 7) & 7) << 4);
                    bfr[bn] = *(const bf16x8*)((const char*)Bs + P);
                }
#pragma unroll
                for (int am = 0; am < 4; am++)
#pragma unroll
                    for (int bn = 0; bn < 4; bn++)
                        acc[am][bn] = __builtin_amdgcn_mfma_f32_16x16x32_bf16(af[am], bfr[bn], acc[am][bn], 0, 0, 0);
            }
            __syncthreads();
        }
        // z-step (BK=32), 64B rows
        {
            const unsigned slabZ = (unsigned)c * (unsigned)(M_TOT * ZD);
#pragma unroll
            for (int i = 0; i < 2; i++)
                gload16(Fz + slabZ + offZA[i], (char*)As + (t + i * 256) * 16);
            unsigned cb = (unsigned)c * PZ;
#pragma unroll
            for (int i = 0; i < 2; i++)
                gload16(Bt + offBz + (unsigned)i * (64u * KPZ) + cb, (char*)Bs + (t + i * 256) * 16);
            __syncthreads();
            bf16x8 af[4], bfr[4];
#pragma unroll
            for (int am = 0; am < 4; am++) {
                int L = (arow + am * 16) * 64 + kqo * 2;
                int P = L ^ (((L >> 6) & 3) << 4);
                af[am] = *(const bf16x8*)((const char*)As + P);
            }
#pragma unroll
            for (int bn = 0; bn < 4; bn++) {
                int L = (brow + bn * 16) * 64 + kqo * 2;
                int P = L ^ (((L >> 6) & 3) << 4);
                bfr[bn] = *(const bf16x8*)((const char*)Bs + P);
            }
#pragma unroll
            for (int am = 0; am < 4; am++)
#pragma unroll
                for (int bn = 0; bn < 4; bn++)
                    acc[am][bn] = __builtin_amdgcn_mfma_f32_16x16x32_bf16(af[am], bfr[bn], acc[am][bn], 0, 0, 0);
            __syncthreads();
        }
        // fold
#pragma unroll
        for (int am = 0; am < 4; am++)
#pragma unroll
            for (int bn = 0; bn < 4; bn++)
#pragma unroll
                for (int ep = 0; ep < 2; ep++) {
                    float f0 = up_lo(outp[am][bn][ep]);
                    float f1 = up_hi(outp[am][bn][ep]);
                    f0 = rb(f0 + rb(acc[am][bn][ep * 2 + 0]));
                    f1 = rb(f1 + rb(acc[am][bn][ep * 2 + 1]));
                    outp[am][bn][ep] = pk2(f0, f1);
                }
        if (c == 0) {
#pragma unroll
            for (int bn = 0; bn < 4; bn++) {
                float bv = rb(bias[ccol0 + bn * 16 + lcol]);
#pragma unroll
                for (int am = 0; am < 4; am++)
#pragma unroll
                    for (int ep = 0; ep < 2; ep++) {
                        float f0 = rb(up_lo(outp[am][bn][ep]) + bv);
                        float f1 = rb(up_hi(outp[am][bn][ep]) + bv);
                        outp[am][bn][ep] = pk2(f0, f1);
                    }
            }
        }
    }

#pragma unroll
    for (int bn = 0; bn < 4; bn++) {
        int col = ccol0 + bn * 16 + lcol;
#pragma unroll
        for (int am = 0; am < 4; am++) {
            int row = crow0 + am * 16 + lrow4;
            C[(size_t)(row + 0) * N + col] = (unsigned short)(outp[am][bn][0] & 0xFFFFu);
            C[(size_t)(row + 1) * N + col] = (unsigned short)(outp[am][bn][0] >> 16);
            C[(size_t)(row + 2) * N + col] = (unsigned short)(outp[am][bn][1] & 0xFFFFu);
            C[(size_t)(row + 3) * N + col] = (unsigned short)(outp[am][bn][1] >> 16);
        }
    }
}

// ============================ GEMM1: dense-A (slab F1), BM128 x BN128, 256 thr, BK=64
#define BM1 128
#define BN1 128

__global__ __launch_bounds__(256, 4) void gemm1_k(const bf16* __restrict__ A,
                                                  const bf16* __restrict__ Bt,
                                                  const float* __restrict__ bias,
                                                  float* __restrict__ C,
                                                  int Mrows, unsigned slabA) {
    __shared__ __align__(16) bf16 As[BM1 * 64];   // 16 KB
    __shared__ __align__(16) bf16 Bs[BN1 * 64];   // 16 KB

    const int N = OUT1, IN = HID, K = K1;
    const int nbm = Mrows / BM1, nbn = N / BN1;
    int pid = blockIdx.x;
    int width = GROUP_M * nbn;
    int group_id = pid / width;
    int first_m = group_id * GROUP_M;
    int gsz = min(nbm - first_m, GROUP_M);
    int mb = first_m + (pid % width) % gsz;
    int nb = (pid % width) / gsz;

    int t = threadIdx.x;
    int lane = t & 63, wid = t >> 6;
    int wm = wid >> 1, wn = wid & 1;              // 2x2 waves, 64x64 each

    const unsigned colx = (unsigned)(((t & 7) ^ ((t >> 3) & 7)) * 8);
    const unsigned offA = (unsigned)(mb * BM1 + (t >> 3)) * (unsigned)IN + colx;  // slab-local
    const unsigned offB = (unsigned)(nb * BN1 + (t >> 3)) * (unsigned)K + colx;

    const int arow = wm * 64 + (lane & 15);
    const int brow = wn * 64 + (lane & 15);
    const int kqo = (lane >> 4) * 8;

    const int lcol = lane & 15, lrow4 = (lane >> 4) * 4;
    const int crow0 = mb * BM1 + wm * 64;
    const int ccol0 = nb * BN1 + wn * 64;

    unsigned outp[4][4][2] = {};

    for (int c = 0; c < NCH; c++) {
        f32x4 acc[4][4] = {};
        const unsigned slab = (unsigned)c * slabA;
        for (int ks = 0; ks < IN; ks += 64) {
            unsigned cbB = (unsigned)c * (unsigned)IN + ks;
#pragma unroll
            for (int i = 0; i < 4; i++) {
                gload16(A + slab + offA + (unsigned)i * (32u * (unsigned)IN) + ks,
                        (char*)As + (t + i * 256) * 16);
                gload16(Bt + offB + (unsigned)i * (32u * (unsigned)K) + cbB,
                        (char*)Bs + (t + i * 256) * 16);
            }
            __syncthreads();
#pragma unroll
            for (int h = 0; h < 2; h++) {
                bf16x8 af[4], bfr[4];
#pragma unroll
                for (int am = 0; am < 4; am++) {
                    int L = (arow + am * 16) * 128 + h * 64 + kqo * 2;
                    int P = L ^ (((L >> 7) & 7) << 4);
                    af[am] = *(const bf16x8*)((const char*)As + P);
                }
#pragma unroll
                for (int bn = 0; bn < 4; bn++) {
                    int L = (brow + bn * 16) * 128 + h * 64 + kqo * 2;
                    int P = L ^ (((L >> 7) & 7) << 4);
                    bfr[bn] = *(const bf16x8*)((const char*)Bs + P);
                }
#pragma unroll
                for (int am = 0; am < 4; am++)
#pragma unroll
                    for (int bn = 0; bn < 4; bn++)
                        acc[am][bn] = __builtin_amdgcn_mfma_f32_16x16x32_bf16(af[am], bfr[bn], acc[am][bn], 0, 0, 0);
            }
            __syncthreads();
        }
#pragma unroll
        for (int am = 0; am < 4; am++)
#pragma unroll
            for (int bn = 0; bn < 4; bn++)
#pragma unroll
                for (int ep = 0; ep < 2; ep++) {
                    float f0 = up_lo(outp[am][bn][ep]);
                    float f1 = up_hi(outp[am][bn][ep]);
                    f0 = rb(f0 + rb(acc[am][bn][ep * 2 + 0]));
                    f1 = rb(f1 + rb(acc[am][bn][ep * 2 + 1]));
                    outp[am][bn][ep] = pk2(f0, f1);
                }
        if (c == 0) {
#pragma unroll
            for (int bn = 0; bn < 4; bn++) {
                float bv = rb(bias[ccol0 + bn * 16 + lcol]);
#pragma unroll
                for (int am = 0; am < 4; am++)
#pragma unroll
                    for (int ep = 0; ep < 2; ep++) {
                        float f0 = rb(up_lo(outp[am][bn][ep]) + bv);
                        float f1 = rb(up_hi(outp[am][bn][ep]) + bv);
                        outp[am][bn][ep] = pk2(f0, f1);
                    }
            }
        }
    }

#pragma unroll
    for (int bn = 0; bn < 4; bn++) {
        int col = ccol0 + bn * 16 + lcol;
#pragma unroll
        for (int am = 0; am < 4; am++) {
            int row = crow0 + am * 16 + lrow4;
            C[(size_t)(row + 0) * N + col] = up_lo(outp[am][bn][0]);
            C[(size_t)(row + 1) * N + col] = up_hi(outp[am][bn][0]);
            C[(size_t)(row + 2) * N + col] = up_lo(outp[am][bn][1]);
            C[(size_t)(row + 3) * N + col] = up_hi(outp[am][bn][1]);
        }
    }
}

// ------------------------------------------------------------------ host
extern "C" void kernel_launch(void* const* d_in, const int* in_sizes, int n_in,
                              void* d_out, int out_size, void* d_ws, size_t ws_size,
                              hipStream_t stream) {
    const float* h_x   = (const float*)d_in[0];
    const int*   tp    = (const int*)d_in[1];
    const float* z     = (const float*)d_in[2];
    const float* pe    = (const float*)d_in[3];
    const float* base0 = (const float*)d_in[4];
    const float* poly0 = (const float*)d_in[5];
    const float* rms0  = (const float*)d_in[6];
    const float* base1 = (const float*)d_in[7];
    const float* poly1 = (const float*)d_in[8];
    const float* rms1  = (const float*)d_in[9];
    float* out = (float*)d_out;

    char* ws = (char*)d_ws;
    size_t off = 0;
    bf16* wctx  = (bf16*)(ws + off); off += (size_t)HID * KCTX * 2;
    bf16* wposz = (bf16*)(ws + off); off += (size_t)HID * KPZ * 2;
    bf16* wb1   = (bf16*)(ws + off); off += (size_t)OUT1 * K1 * 2;
    float* bias0 = (float*)(ws + off); off += HID * 4;
    float* bias1 = (float*)(ws + off); off += OUT1 * 4;
    float* partial = (float*)(ws + off); off += 32 * HID * 4;
    bf16* Fctx = (bf16*)(ws + off); off += (size_t)B_SZ * KCTX * 2;
    float* ctx_part = (float*)(ws + off); off += (size_t)B_SZ * NCH * HID * 4;
    bf16* Fpos = (bf16*)(ws + off); off += (size_t)NCH * NPOS * 1024 * 2;  // 109 MB, slab-major
    bf16* Fz   = (bf16*)(ws + off); off += (size_t)NCH * M_TOT * ZD * 2;   // 13.6 MB, slab-major
    bf16* H0   = (bf16*)(ws + off); off += (size_t)M_TOT * HID * 2;        // 67 MB
    size_t fixed = off;

    bf16* F1 = (bf16*)(ws + off);
    size_t avail = ws_size > fixed ? ws_size - fixed : 0;
    long long chunk_ll = (long long)(avail / ((size_t)K1 * 2));
    int chunk = (int)(chunk_ll > M_TOT ? M_TOT : chunk_ll);
    chunk &= ~127;
    if (chunk < 128) chunk = 128;
    const unsigned slabF1 = (unsigned)chunk * HID;

    dim3 tb(32, 8);
    convert_w0<<<dim3(IN0 / 32, HID / 32, NCH), tb, 0, stream>>>(base0, poly0, wctx, wposz);
    convert_w<<<dim3(HID / 32, OUT1 / 32, NCH), tb, 0, stream>>>(base1, poly1, wb1, HID, OUT1);
    col_sum_s1<<<dim3(HID / 64, 32), dim3(64, 4), 0, stream>>>(poly0, partial, IN0, HID);
    col_sum_s2<<<HID / 256, 256, 0, stream>>>(partial, bias0, HID);
    col_sum_s1<<<dim3(OUT1 / 64, 32), dim3(64, 4), 0, stream>>>(poly1, partial, HID, OUT1);
    col_sum_s2<<<OUT1 / 256, 256, 0, stream>>>(partial, bias1, OUT1);
    build_fctx<<<8, 256, 0, stream>>>(h_x, Fctx);
    ctx_dot<<<dim3(HID / 64, NCH, B_SZ), dim3(64, 4), 0, stream>>>(Fctx, wctx, ctx_part);
    build_fpos<<<(NPOS * 128) / 256, 256, 0, stream>>>(pe, Fpos);
    build_fz<<<(M_TOT * (ZD / 8)) / 256, 256, 0, stream>>>(z, Fz);

    gemm0_k<<<(M_TOT / BM0) * (HID / BN0), 256, 0, stream>>>(
        Fpos, Fz, tp, wposz, bias0, ctx_part, (unsigned short*)H0);

    for (int m0 = 0; m0 < M_TOT; m0 += chunk) {
        int rows = (M_TOT - m0 < chunk) ? (M_TOT - m0) : chunk;
        rmsnorm_feat<<<rows, 256, 0, stream>>>(H0 + (size_t)m0 * HID, rms0, F1, (int)slabF1);
        float* o = out + (size_t)m0 * OUT1;
        gemm1_k<<<(rows / BM1) * (OUT1 / BN1), 256, 0, stream>>>(F1, wb1, bias1, o, rows, slabF1);
    }
    rmsnorm_k<OUT1><<<M_TOT, 256, 0, stream>>>(out, rms1);
}